// Round 1
// baseline (139.719 us; speedup 1.0000x reference)
//
#include <hip/hip_runtime.h>
#include <hip/hip_bf16.h>
#include <stdint.h>

#define N_ROWS 32768
#define DIM    256
#define KCODES 8192
#define KSPLIT 4
#define BM     256
#define WM     64
#define BN     64
#define NT     (KCODES / KSPLIT / BN)   /* 32 tiles per block */
#define THREADS 256

typedef __bf16 bf16;
typedef bf16  v8bf  __attribute__((ext_vector_type(8)));
typedef float v4f   __attribute__((ext_vector_type(4)));

__device__ __forceinline__ uint16_t f2bf(float f) {
  bf16 h = (bf16)f; uint16_t u; __builtin_memcpy(&u, &h, 2); return u;
}

__device__ __forceinline__ void gload_lds16(const bf16* g, uint8_t* l) {
  __builtin_amdgcn_global_load_lds((const __attribute__((address_space(1))) uint32_t*)g,
                                   (__attribute__((address_space(3))) uint32_t*)l, 16, 0, 0);
}

// ---------------- Kernel A: weight fp32 -> bf16, bprime = 1 + sum(w^2) -------
__global__ void kconv(const float* __restrict__ w, bf16* __restrict__ wb,
                      float* __restrict__ bp) {
  const int row = blockIdx.x, t = threadIdx.x;
  float v = w[row * DIM + t];
  wb[row * DIM + t] = (bf16)v;
  float s = v * v;
  for (int o = 32; o; o >>= 1) s += __shfl_down(s, o, 64);
  __shared__ float ps[4];
  if ((t & 63) == 0) ps[t >> 6] = s;
  __syncthreads();
  if (t == 0) bp[row] = 1.0f + (ps[0] + ps[1] + ps[2] + ps[3]);
}

// ---------------- Kernel B: MFMA distance argmin -----------------------------
__global__ __launch_bounds__(THREADS, 2) void kmain(
    const float* __restrict__ x, const bf16* __restrict__ wb,
    const float* __restrict__ bp, uint64_t* __restrict__ cand) {
  __shared__ __align__(16) uint8_t sm[65536];
  const int bm = blockIdx.x;            // 0..127 row-block
  const int sp = blockIdx.y;            // 0..3 K split
  const int rb = bm * BM;
  const int k0 = sp * (KCODES / KSPLIT);
  const int t = threadIdx.x;
  const int w = t >> 6, l = t & 63, q = l >> 4, l15 = l & 15;

  // ---- load A fragments (x rows, bf16) to registers via 2 LDS passes ----
  v8bf afr[4][8];
  for (int p = 0; p < 2; ++p) {
    for (int it = 0; it < 32; ++it) {
      int e = it * 1024 + t * 4;
      int r = e >> 8, c = e & 255;
      const float4 xv = *(const float4*)(x + (size_t)(rb + p * 128 + r) * DIM + c);
      uint32_t u0 = (uint32_t)f2bf(xv.x) | ((uint32_t)f2bf(xv.y) << 16);
      uint32_t u1 = (uint32_t)f2bf(xv.z) | ((uint32_t)f2bf(xv.w) << 16);
      int chunk = (c >> 3) ^ (r & 7);
      uint32_t* d = (uint32_t*)(sm + r * 512 + chunk * 16 + (c & 7) * 2);
      d[0] = u0; d[1] = u1;
    }
    __syncthreads();
    if ((w >> 1) == p) {
      int wrow0 = w * WM - p * 128;     // 0 or 64 within this pass
#pragma unroll
      for (int mi = 0; mi < 4; ++mi)
#pragma unroll
        for (int ks = 0; ks < 8; ++ks) {
          int r = wrow0 + mi * 16 + l15;
          int chunk = (ks * 4 + q) ^ (r & 7);
          afr[mi][ks] = *(const v8bf*)(sm + r * 512 + chunk * 16);
        }
    }
    __syncthreads();
  }

  // ---- running packed argmin: ((fp32bits of 1+b-2*dot) << 8) | (kt*4+nb) ----
  uint32_t mp[4][4];
#pragma unroll
  for (int mi = 0; mi < 4; ++mi)
#pragma unroll
    for (int j = 0; j < 4; ++j) mp[mi][j] = 0xFFFFFFFFu;

  auto stage = [&](int kt, int buf) {
    const bf16* src = wb + (size_t)(k0 + kt * BN) * DIM;
#pragma unroll
    for (int i = 0; i < 8; ++i) {
      int r0 = w * 16 + 2 * i;
      int r = r0 + (l >> 5);
      int c = (l & 31) ^ (r & 7);                 // pre-swizzled source chunk
      gload_lds16(src + (size_t)r * DIM + c * 8,
                  sm + buf * 32768 + r0 * 512);   // wave-uniform LDS base
    }
  };

  stage(0, 0);
  __syncthreads();
  for (int kt = 0; kt < NT; ++kt) {
    const int cur = kt & 1;
    if (kt + 1 < NT) stage(kt + 1, cur ^ 1);
    const uint8_t* sb = sm + cur * 32768;
#pragma unroll
    for (int nb = 0; nb < 4; ++nb) {
      float bpv = bp[k0 + kt * BN + nb * 16 + l15];
      v4f acc[4];
#pragma unroll
      for (int mi = 0; mi < 4; ++mi) acc[mi] = (v4f){0.f, 0.f, 0.f, 0.f};
#pragma unroll
      for (int ks = 0; ks < 8; ++ks) {
        int r = nb * 16 + l15;
        int chunk = (ks * 4 + q) ^ (r & 7);
        v8bf bfr = *(const v8bf*)(sb + r * 512 + chunk * 16);
#pragma unroll
        for (int mi = 0; mi < 4; ++mi)
          acc[mi] = __builtin_amdgcn_mfma_f32_16x16x32_bf16(afr[mi][ks], bfr,
                                                            acc[mi], 0, 0, 0);
      }
      const uint32_t slot = (uint32_t)(kt * 4 + nb);
#pragma unroll
      for (int mi = 0; mi < 4; ++mi)
#pragma unroll
        for (int j = 0; j < 4; ++j) {
          float s = fmaf(-2.0f, acc[mi][j], bpv);   // in [0.92, 1.08]
          uint32_t pv = (__float_as_uint(s) << 8) | slot;
          mp[mi][j] = pv < mp[mi][j] ? pv : mp[mi][j];
        }
    }
    __syncthreads();
  }

  // ---- cross-lane (16 cols) argmin reduce, write candidates ----
#pragma unroll
  for (int mi = 0; mi < 4; ++mi)
#pragma unroll
    for (int j = 0; j < 4; ++j) {
      uint32_t pv = mp[mi][j];
      uint32_t slot = pv & 255u;
      uint32_t kglob = (uint32_t)k0 + (slot >> 2) * 64 + (slot & 3) * 16 + l15;
      uint64_t P = ((uint64_t)(pv >> 8) << 13) | (uint64_t)kglob;
#pragma unroll
      for (int o = 1; o < 16; o <<= 1) {
        uint32_t lo = (uint32_t)P, hi = (uint32_t)(P >> 32);
        uint32_t olo = __shfl_xor(lo, o, 64), ohi = __shfl_xor(hi, o, 64);
        uint64_t other = ((uint64_t)ohi << 32) | olo;
        P = other < P ? other : P;
      }
      if (l15 == 0) {
        int row = rb + w * WM + mi * 16 + q * 4 + j;
        cand[(size_t)row * KSPLIT + sp] = P;
      }
    }
}

// ---------------- Kernel C: combine splits, gather, out, loss partials -------
__global__ void kout(const float* __restrict__ x, const float* __restrict__ wgt,
                     const uint64_t* __restrict__ cand, float* __restrict__ out,
                     float* __restrict__ partial) {
  const int t = threadIdx.x;
  const int rb = blockIdx.x * 64;
  __shared__ int sk[64];
  __shared__ float red[4];
  if (t < 64) {
    const uint64_t* c = cand + (size_t)(rb + t) * KSPLIT;
    uint64_t P = c[0];
    P = c[1] < P ? c[1] : P;
    P = c[2] < P ? c[2] : P;
    P = c[3] < P ? c[3] : P;
    sk[t] = (int)(P & 8191u);
  }
  __syncthreads();
  float acc = 0.f;
  for (int r = 0; r < 64; ++r) {
    int k = sk[r];
    float qv = wgt[(size_t)k * DIM + t];
    float xv = x[(size_t)(rb + r) * DIM + t];
    out[(size_t)(rb + r) * DIM + t] = qv;
    float d = xv - qv;
    acc = fmaf(d, d, acc);
  }
  for (int o = 32; o; o >>= 1) acc += __shfl_down(acc, o, 64);
  if ((t & 63) == 0) red[t >> 6] = acc;
  __syncthreads();
  if (t == 0) partial[blockIdx.x] = red[0] + red[1] + red[2] + red[3];
}

// ---------------- Kernel D: final loss ---------------------------------------
__global__ void kloss(const float* __restrict__ partial, float* __restrict__ lossout) {
  const int t = threadIdx.x;
  float s = partial[t] + partial[t + 256];
  for (int o = 32; o; o >>= 1) s += __shfl_down(s, o, 64);
  __shared__ float red[4];
  if ((t & 63) == 0) red[t >> 6] = s;
  __syncthreads();
  if (t == 0) lossout[0] = 1.5f * (red[0] + red[1] + red[2] + red[3]) /
                           (float)((size_t)N_ROWS * DIM);
}

extern "C" void kernel_launch(void* const* d_in, const int* in_sizes, int n_in,
                              void* d_out, int out_size, void* d_ws, size_t ws_size,
                              hipStream_t stream) {
  const float* x   = (const float*)d_in[0];
  const float* wgt = (const float*)d_in[1];
  float* out = (float*)d_out;
  uint8_t* ws = (uint8_t*)d_ws;
  bf16*     wb      = (bf16*)ws;                                   // 4 MB
  float*    bp      = (float*)(ws + (4u << 20));                   // 32 KB
  uint64_t* cand    = (uint64_t*)(ws + (4u << 20) + (32u << 10));  // 1 MB
  float*    partial = (float*)(ws + (4u << 20) + (32u << 10) + (1u << 20)); // 2 KB

  kconv<<<KCODES, 256, 0, stream>>>(wgt, wb, bp);
  dim3 g(N_ROWS / BM, KSPLIT);
  kmain<<<g, THREADS, 0, stream>>>(x, wb, bp, cand);
  kout<<<N_ROWS / 64, 256, 0, stream>>>(x, wgt, cand, out, partial);
  kloss<<<1, 256, 0, stream>>>(partial, out + (size_t)N_ROWS * DIM);
}

// Round 2
// 103.850 us; speedup vs baseline: 1.3454x; 1.3454x over previous
//
#include <hip/hip_runtime.h>
#include <stdint.h>

#define N_ROWS 32768
#define DIM    256
#define KCODES 8192
#define KSPLIT 4
#define KPS    (KCODES / KSPLIT)   /* 2048 codes per split */
#define BM     256
#define BN     64
#define NT     (KPS / BN)          /* 32 tiles */
#define THREADS 256

typedef int   v8i  __attribute__((ext_vector_type(8)));
typedef float v16f __attribute__((ext_vector_type(16)));

__device__ __forceinline__ void gload_lds16(const void* g, void* l) {
  __builtin_amdgcn_global_load_lds((const __attribute__((address_space(1))) uint32_t*)g,
                                   (__attribute__((address_space(3))) uint32_t*)l, 16, 0, 0);
}

// ---------------- Kernel A: weight fp32 -> fp8 (x 2^13), bp = 1 + sum(w^2) ---
__global__ void kconv(const float* __restrict__ wgt, uint32_t* __restrict__ wb8,
                      float* __restrict__ bp) {
  const int code = blockIdx.x * 4 + (threadIdx.x >> 6);
  const int l = threadIdx.x & 63;
  float4 v = *(const float4*)(wgt + (size_t)code * DIM + l * 4);
  float s = v.x * v.x + v.y * v.y + v.z * v.z + v.w * v.w;
  int u = __builtin_amdgcn_cvt_pk_fp8_f32(v.x * 8192.f, v.y * 8192.f, 0, false);
  u = __builtin_amdgcn_cvt_pk_fp8_f32(v.z * 8192.f, v.w * 8192.f, u, true);
  wb8[(size_t)code * 64 + l] = (uint32_t)u;
  for (int o = 32; o; o >>= 1) s += __shfl_down(s, o, 64);
  if (l == 0) bp[code] = 1.0f + s;
}

// ---------------- Kernel B: fp8 MX-MFMA distance argmin ----------------------
__global__ __launch_bounds__(THREADS, 2) void kmain(
    const float* __restrict__ x, const uint32_t* __restrict__ wb8,
    const float* __restrict__ bp, uint64_t* __restrict__ cand) {
  __shared__ __align__(16) uint8_t sm[32768];
  const int bm = blockIdx.x;           // row block
  const int sp = blockIdx.y;           // K split
  const int rb = bm * BM;
  const int k0 = sp * KPS;
  const int t = threadIdx.x;
  const int wv = t >> 6, l = t & 63, l31 = l & 31, h = l >> 5;

  // ---- A prologue: x rows -> fp8 registers, 2 LDS passes of 128 rows ----
  v8i afr[2][4];
  for (int p = 0; p < 2; ++p) {
    for (int it = 0; it < 32; ++it) {
      int e = it * 1024 + t * 4;
      int r = e >> 8, cb = e & 255;
      float4 xv = *(const float4*)(x + (size_t)(rb + p * 128 + r) * DIM + cb);
      int u = __builtin_amdgcn_cvt_pk_fp8_f32(xv.x, xv.y, 0, false);
      u = __builtin_amdgcn_cvt_pk_fp8_f32(xv.z, xv.w, u, true);
      *(int*)(sm + r * 256 + (((cb >> 5) ^ (r & 7)) << 5) + (cb & 31)) = u;
    }
    __syncthreads();
    if ((wv >> 1) == p) {
      int rw = (wv & 1) * 64;
#pragma unroll
      for (int mi = 0; mi < 2; ++mi)
#pragma unroll
        for (int ks = 0; ks < 4; ++ks) {
          int r = rw + mi * 32 + l31;
          int c32 = ks * 2 + h;
          afr[mi][ks] = *(const v8i*)(sm + r * 256 + ((c32 ^ (r & 7)) << 5));
        }
    }
    __syncthreads();
  }

  uint32_t mp[2][16];
#pragma unroll
  for (int mi = 0; mi < 2; ++mi)
#pragma unroll
    for (int j = 0; j < 16; ++j) mp[mi][j] = 0xFFFFFFFFu;

  auto stage = [&](int kt, int buf) {
    const uint32_t* src = wb8 + (size_t)(k0 + kt * BN) * 64;
#pragma unroll
    for (int i = 0; i < 4; ++i) {
      int r = wv * 16 + i * 4 + (l >> 4);
      int p16 = l & 15;
      int srcoff = r * 64 + (((p16 >> 1) ^ (r & 7)) << 3) + (p16 & 1) * 4;
      gload_lds16(src + srcoff, sm + buf * 16384 + (wv * 16 + i * 4) * 256);
    }
  };

  float bpc0, bpc1;
  float bpn0 = bp[k0 + l31];
  float bpn1 = bp[k0 + 32 + l31];
  stage(0, 0);
  __syncthreads();

  for (int kt = 0; kt < NT; ++kt) {
    const int cur = kt & 1;
    if (kt + 1 < NT) stage(kt + 1, cur ^ 1);
    bpc0 = bpn0; bpc1 = bpn1;
    if (kt + 1 < NT) {
      bpn0 = bp[k0 + (kt + 1) * 64 + l31];
      bpn1 = bp[k0 + (kt + 1) * 64 + 32 + l31];
    }
    const uint8_t* sb = sm + cur * 16384;
#pragma unroll
    for (int nb = 0; nb < 2; ++nb) {
      v16f acc0, acc1;
#pragma unroll
      for (int z = 0; z < 16; ++z) { acc0[z] = 0.f; acc1[z] = 0.f; }
      __builtin_amdgcn_s_setprio(1);
#pragma unroll
      for (int ks = 0; ks < 4; ++ks) {
        int r = nb * 32 + l31;
        int c32 = ks * 2 + h;
        v8i bf = *(const v8i*)(sb + r * 256 + ((c32 ^ (r & 7)) << 5));
        acc0 = __builtin_amdgcn_mfma_scale_f32_32x32x64_f8f6f4(
            afr[0][ks], bf, acc0, 0, 0, 0, 127, 0, 127);
        acc1 = __builtin_amdgcn_mfma_scale_f32_32x32x64_f8f6f4(
            afr[1][ks], bf, acc1, 0, 0, 0, 127, 0, 127);
      }
      __builtin_amdgcn_s_setprio(0);
      const float bpv = nb ? bpc1 : bpc0;
      const uint32_t slot = (uint32_t)(kt * 2 + nb);
#pragma unroll
      for (int j = 0; j < 16; ++j) {
        float s0 = fmaf(acc0[j], -0.000244140625f, bpv);  // bp - 2*dot (2^-13 scale)
        uint32_t pv0 = (__float_as_uint(s0) << 8) | slot;
        mp[0][j] = pv0 < mp[0][j] ? pv0 : mp[0][j];
        float s1 = fmaf(acc1[j], -0.000244140625f, bpv);
        uint32_t pv1 = (__float_as_uint(s1) << 8) | slot;
        mp[1][j] = pv1 < mp[1][j] ? pv1 : mp[1][j];
      }
    }
    __syncthreads();
  }

  // ---- cross-lane argmin over the 32 code-columns, write candidates ----
#pragma unroll
  for (int mi = 0; mi < 2; ++mi)
#pragma unroll
    for (int j = 0; j < 16; ++j) {
      uint32_t pv = mp[mi][j];
      uint32_t slot = pv & 255u;
      uint32_t kg = (uint32_t)k0 + (slot >> 1) * 64 + (slot & 1) * 32 + l31;
      uint64_t P = ((uint64_t)(pv & 0xFFFFFF00u) << 5) | (uint64_t)kg;
#pragma unroll
      for (int o = 1; o < 32; o <<= 1) {
        uint32_t lo = (uint32_t)P, hi = (uint32_t)(P >> 32);
        uint32_t olo = __shfl_xor(lo, o, 64), ohi = __shfl_xor(hi, o, 64);
        uint64_t other = ((uint64_t)ohi << 32) | olo;
        P = other < P ? other : P;
      }
      if (l31 == 0) {
        int row = rb + wv * 64 + mi * 32 + (j & 3) + 8 * (j >> 2) + 4 * h;
        cand[(size_t)row * KSPLIT + sp] = P;
      }
    }
}

// ---------------- Kernel C: combine splits, gather, out, loss partials -------
__global__ void kout(const float* __restrict__ x, const float* __restrict__ wgt,
                     const uint64_t* __restrict__ cand, float* __restrict__ out,
                     float* __restrict__ partial) {
  const int t = threadIdx.x;
  const int rb = blockIdx.x * 64;
  __shared__ int sk[64];
  __shared__ float red[4];
  if (t < 64) {
    const uint64_t* c = cand + (size_t)(rb + t) * KSPLIT;
    uint64_t P = c[0];
    P = c[1] < P ? c[1] : P;
    P = c[2] < P ? c[2] : P;
    P = c[3] < P ? c[3] : P;
    sk[t] = (int)(P & 8191u);
  }
  __syncthreads();
  float acc = 0.f;
  for (int r = 0; r < 64; ++r) {
    int k = sk[r];
    float qv = wgt[(size_t)k * DIM + t];
    float xv = x[(size_t)(rb + r) * DIM + t];
    out[(size_t)(rb + r) * DIM + t] = qv;
    float d = xv - qv;
    acc = fmaf(d, d, acc);
  }
  for (int o = 32; o; o >>= 1) acc += __shfl_down(acc, o, 64);
  if ((t & 63) == 0) red[t >> 6] = acc;
  __syncthreads();
  if (t == 0) partial[blockIdx.x] = red[0] + red[1] + red[2] + red[3];
}

// ---------------- Kernel D: final loss ---------------------------------------
__global__ void kloss(const float* __restrict__ partial, float* __restrict__ lossout) {
  const int t = threadIdx.x;
  float s = partial[t] + partial[t + 256];
  for (int o = 32; o; o >>= 1) s += __shfl_down(s, o, 64);
  __shared__ float red[4];
  if ((t & 63) == 0) red[t >> 6] = s;
  __syncthreads();
  if (t == 0) lossout[0] = 1.5f * (red[0] + red[1] + red[2] + red[3]) /
                           (float)((size_t)N_ROWS * DIM);
}

extern "C" void kernel_launch(void* const* d_in, const int* in_sizes, int n_in,
                              void* d_out, int out_size, void* d_ws, size_t ws_size,
                              hipStream_t stream) {
  const float* x   = (const float*)d_in[0];
  const float* wgt = (const float*)d_in[1];
  float* out = (float*)d_out;
  uint8_t* ws = (uint8_t*)d_ws;
  uint32_t* wb8     = (uint32_t*)ws;                                    // 2 MB
  float*    bp      = (float*)(ws + (2u << 20));                        // 32 KB
  uint64_t* cand    = (uint64_t*)(ws + (2u << 20) + (32u << 10));       // 1 MB
  float*    partial = (float*)(ws + (2u << 20) + (32u << 10) + (1u << 20)); // 2 KB

  kconv<<<KCODES / 4, 256, 0, stream>>>(wgt, wb8, bp);
  dim3 g(N_ROWS / BM, KSPLIT);
  kmain<<<g, THREADS, 0, stream>>>(x, wb8, bp, cand);
  kout<<<N_ROWS / 64, 256, 0, stream>>>(x, wgt, cand, out, partial);
  kloss<<<1, 256, 0, stream>>>(partial, out + (size_t)N_ROWS * DIM);
}

// Round 3
// 103.350 us; speedup vs baseline: 1.3519x; 1.0048x over previous
//
#include <hip/hip_runtime.h>
#include <stdint.h>

#define N_ROWS 32768
#define DIM    256
#define KCODES 8192
#define KSPLIT 4
#define KPS    (KCODES / KSPLIT)   /* 2048 codes per split */
#define BM     256
#define BN     64
#define NT     (KPS / BN)          /* 32 tiles */
#define THREADS 256

typedef int   v4i  __attribute__((ext_vector_type(4)));
typedef int   v8i  __attribute__((ext_vector_type(8)));
typedef float v16f __attribute__((ext_vector_type(16)));

__device__ __forceinline__ void gload_lds16(const void* g, void* l) {
  __builtin_amdgcn_global_load_lds((const __attribute__((address_space(1))) uint32_t*)g,
                                   (__attribute__((address_space(3))) uint32_t*)l, 16, 0, 0);
}

// ---------------- Kernel A: weight fp32 -> fp8 (x 2^13), bp = 1 + sum(w^2) ---
__global__ void kconv(const float* __restrict__ wgt, uint32_t* __restrict__ wb8,
                      float* __restrict__ bp) {
  const int code = blockIdx.x * 4 + (threadIdx.x >> 6);
  const int l = threadIdx.x & 63;
  float4 v = *(const float4*)(wgt + (size_t)code * DIM + l * 4);
  float s = v.x * v.x + v.y * v.y + v.z * v.z + v.w * v.w;
  int u = __builtin_amdgcn_cvt_pk_fp8_f32(v.x * 8192.f, v.y * 8192.f, 0, false);
  u = __builtin_amdgcn_cvt_pk_fp8_f32(v.z * 8192.f, v.w * 8192.f, u, true);
  wb8[(size_t)code * 64 + l] = (uint32_t)u;
  for (int o = 32; o; o >>= 1) s += __shfl_down(s, o, 64);
  if (l == 0) bp[code] = 1.0f + s;
}

// ---------------- Kernel B: fp8 MX-MFMA distance argmin ----------------------
__global__ __launch_bounds__(THREADS, 2) void kmain(
    const float* __restrict__ x, const uint32_t* __restrict__ wb8,
    const float* __restrict__ bp, uint64_t* __restrict__ cand) {
  __shared__ __align__(16) uint8_t sm[49152];    // 3 x 16KB B buffers (A reuses 32KB)
  __shared__ __align__(16) float bpl[KPS];       // 8KB
  const int rb = blockIdx.x * BM;
  const int sp = blockIdx.y;
  const int k0 = sp * KPS;
  const int t = threadIdx.x;
  const int wv = t >> 6, l = t & 63, l31 = l & 31, h = l >> 5;
  const int m7 = l31 & 7;

  // ---- bp slice -> LDS (linear, 8 x 1KB chunks) ----
#pragma unroll
  for (int j = 0; j < 2; ++j)
    gload_lds16(bp + k0 + (wv * 2 + j) * 256 + l * 4,
                (uint8_t*)bpl + (wv * 2 + j) * 1024);

  // ---- A prologue: x rows -> fp8 -> LDS (16B-swizzled) -> registers ----
  v8i afr[2][4];
  for (int p = 0; p < 2; ++p) {
    for (int it = 0; it < 32; ++it) {
      int e = it * 1024 + t * 4;
      int r = e >> 8, cb = e & 255;
      float4 xv = *(const float4*)(x + (size_t)(rb + p * 128 + r) * DIM + cb);
      int u = __builtin_amdgcn_cvt_pk_fp8_f32(xv.x, xv.y, 0, false);
      u = __builtin_amdgcn_cvt_pk_fp8_f32(xv.z, xv.w, u, true);
      *(int*)(sm + r * 256 + (((cb >> 4) ^ (r & 7)) << 4) + (cb & 15)) = u;
    }
    __syncthreads();
    if ((wv >> 1) == p) {
      int rw = (wv & 1) * 64;
#pragma unroll
      for (int mi = 0; mi < 2; ++mi)
#pragma unroll
        for (int ks = 0; ks < 4; ++ks) {
          int r = rw + mi * 32 + l31;
          const uint8_t* rp = sm + r * 256;
          int sa = (ks * 4 + h * 2) ^ m7;
          v4i lo = *(const v4i*)(rp + sa * 16);
          v4i hi = *(const v4i*)(rp + (sa ^ 1) * 16);
          v8i f;
          f[0] = lo[0]; f[1] = lo[1]; f[2] = lo[2]; f[3] = lo[3];
          f[4] = hi[0]; f[5] = hi[1]; f[6] = hi[2]; f[7] = hi[3];
          afr[mi][ks] = f;
        }
    }
    __syncthreads();
  }

  uint32_t mp[2][16];
#pragma unroll
  for (int mi = 0; mi < 2; ++mi)
#pragma unroll
    for (int j = 0; j < 16; ++j) mp[mi][j] = 0xFFFFFFFFu;

  auto stage = [&](int kt, int buf) {
    const uint32_t* src = wb8 + (size_t)(k0 + kt * BN) * 64;
#pragma unroll
    for (int i = 0; i < 4; ++i) {
      int r = wv * 16 + i * 4 + (l >> 4);
      int c = (l & 15) ^ (r & 7);                 // pre-swizzled 16B source chunk
      gload_lds16(src + r * 64 + c * 4,
                  sm + buf * 16384 + (wv * 16 + i * 4) * 256);
    }
  };

  stage(0, 0);
  stage(1, 1);
  __syncthreads();                                 // full drain once at start

  int bc = 0, b1 = 1, b2 = 2;
  for (int kt = 0; kt < NT; ++kt) {
    if (kt + 2 < NT) stage(kt + 2, b2);
    const uint8_t* sb = sm + bc * 16384;
#pragma unroll
    for (int nb = 0; nb < 2; ++nb) {
      float bpv = bpl[kt * 64 + nb * 32 + l31];
      v16f acc0, acc1;
#pragma unroll
      for (int z = 0; z < 16; ++z) { acc0[z] = 0.f; acc1[z] = 0.f; }
      __builtin_amdgcn_s_setprio(1);
#pragma unroll
      for (int ks = 0; ks < 4; ++ks) {
        int r = nb * 32 + l31;
        const uint8_t* rp = sb + r * 256;
        int sa = (ks * 4 + h * 2) ^ m7;
        v4i lo = *(const v4i*)(rp + sa * 16);
        v4i hi = *(const v4i*)(rp + (sa ^ 1) * 16);
        v8i bf;
        bf[0] = lo[0]; bf[1] = lo[1]; bf[2] = lo[2]; bf[3] = lo[3];
        bf[4] = hi[0]; bf[5] = hi[1]; bf[6] = hi[2]; bf[7] = hi[3];
        acc0 = __builtin_amdgcn_mfma_scale_f32_32x32x64_f8f6f4(
            afr[0][ks], bf, acc0, 0, 0, 0, 127, 0, 127);
        acc1 = __builtin_amdgcn_mfma_scale_f32_32x32x64_f8f6f4(
            afr[1][ks], bf, acc1, 0, 0, 0, 127, 0, 127);
      }
      __builtin_amdgcn_s_setprio(0);
      const uint32_t slot = (uint32_t)(kt * 2 + nb);
#pragma unroll
      for (int j = 0; j < 16; ++j) {
        float s0 = fmaf(acc0[j], -0.000244140625f, bpv);  // bp - 2*dot (2^-13 scale)
        uint32_t p0 = (__float_as_uint(s0) << 8) | slot;
        mp[0][j] = p0 < mp[0][j] ? p0 : mp[0][j];
        float s1 = fmaf(acc1[j], -0.000244140625f, bpv);
        uint32_t p1 = (__float_as_uint(s1) << 8) | slot;
        mp[1][j] = p1 < mp[1][j] ? p1 : mp[1][j];
      }
    }
    // counted-vmcnt barrier: drain only tile kt+1's stage loads (4), keep
    // tile kt+2's in flight; vmcnt(0) only at the pipeline tail.
    __builtin_amdgcn_sched_barrier(0);
    if (kt + 2 < NT) { asm volatile("s_waitcnt vmcnt(4)" ::: "memory"); }
    else             { asm volatile("s_waitcnt vmcnt(0)" ::: "memory"); }
    __builtin_amdgcn_s_barrier();
    __builtin_amdgcn_sched_barrier(0);
    int tmp = bc; bc = b1; b1 = b2; b2 = tmp;
  }

  // ---- cross-lane argmin over the 32 code-columns, write candidates ----
#pragma unroll
  for (int mi = 0; mi < 2; ++mi)
#pragma unroll
    for (int j = 0; j < 16; ++j) {
      uint32_t pv = mp[mi][j];
      uint32_t slot = pv & 255u;
      uint32_t kg = (uint32_t)k0 + (slot >> 1) * 64 + (slot & 1) * 32 + l31;
      uint64_t P = ((uint64_t)(pv & 0xFFFFFF00u) << 5) | (uint64_t)kg;
#pragma unroll
      for (int o = 1; o < 32; o <<= 1) {
        uint32_t lo = (uint32_t)P, hi = (uint32_t)(P >> 32);
        uint32_t olo = __shfl_xor(lo, o, 64), ohi = __shfl_xor(hi, o, 64);
        uint64_t other = ((uint64_t)ohi << 32) | olo;
        P = other < P ? other : P;
      }
      if (l31 == 0) {
        int row = rb + wv * 64 + mi * 32 + (j & 3) + 8 * (j >> 2) + 4 * h;
        cand[(size_t)row * KSPLIT + sp] = P;
      }
    }
}

// ---------------- Kernel C: combine splits, gather, out, loss partials -------
__global__ void kout(const float* __restrict__ x, const float* __restrict__ wgt,
                     const uint64_t* __restrict__ cand, float* __restrict__ out,
                     float* __restrict__ partial) {
  const int t = threadIdx.x;
  const int rb = blockIdx.x * 64;
  __shared__ int sk[64];
  __shared__ float red[4];
  if (t < 64) {
    const uint64_t* c = cand + (size_t)(rb + t) * KSPLIT;
    uint64_t P = c[0];
    P = c[1] < P ? c[1] : P;
    P = c[2] < P ? c[2] : P;
    P = c[3] < P ? c[3] : P;
    sk[t] = (int)(P & 8191u);
  }
  __syncthreads();
  float acc = 0.f;
  for (int r = 0; r < 64; ++r) {
    int k = sk[r];
    float qv = wgt[(size_t)k * DIM + t];
    float xv = x[(size_t)(rb + r) * DIM + t];
    out[(size_t)(rb + r) * DIM + t] = qv;
    float d = xv - qv;
    acc = fmaf(d, d, acc);
  }
  for (int o = 32; o; o >>= 1) acc += __shfl_down(acc, o, 64);
  if ((t & 63) == 0) red[t >> 6] = acc;
  __syncthreads();
  if (t == 0) partial[blockIdx.x] = red[0] + red[1] + red[2] + red[3];
}

// ---------------- Kernel D: final loss ---------------------------------------
__global__ void kloss(const float* __restrict__ partial, float* __restrict__ lossout) {
  const int t = threadIdx.x;
  float s = partial[t] + partial[t + 256];
  for (int o = 32; o; o >>= 1) s += __shfl_down(s, o, 64);
  __shared__ float red[4];
  if ((t & 63) == 0) red[t >> 6] = s;
  __syncthreads();
  if (t == 0) lossout[0] = 1.5f * (red[0] + red[1] + red[2] + red[3]) /
                           (float)((size_t)N_ROWS * DIM);
}

extern "C" void kernel_launch(void* const* d_in, const int* in_sizes, int n_in,
                              void* d_out, int out_size, void* d_ws, size_t ws_size,
                              hipStream_t stream) {
  const float* x   = (const float*)d_in[0];
  const float* wgt = (const float*)d_in[1];
  float* out = (float*)d_out;
  uint8_t* ws = (uint8_t*)d_ws;
  uint32_t* wb8     = (uint32_t*)ws;                                    // 2 MB
  float*    bp      = (float*)(ws + (2u << 20));                        // 32 KB
  uint64_t* cand    = (uint64_t*)(ws + (2u << 20) + (32u << 10));       // 1 MB
  float*    partial = (float*)(ws + (2u << 20) + (32u << 10) + (1u << 20)); // 2 KB

  kconv<<<KCODES / 4, 256, 0, stream>>>(wgt, wb8, bp);
  dim3 g(N_ROWS / BM, KSPLIT);
  kmain<<<g, THREADS, 0, stream>>>(x, wb8, bp, cand);
  kout<<<N_ROWS / 64, 256, 0, stream>>>(x, wgt, cand, out, partial);
  kloss<<<1, 256, 0, stream>>>(partial, out + (size_t)N_ROWS * DIM);
}